// Round 5
// baseline (183.662 us; speedup 1.0000x reference)
//
#include <hip/hip_runtime.h>
#include <hip/hip_bf16.h>

typedef __attribute__((ext_vector_type(8))) short bf16x8;
typedef __attribute__((ext_vector_type(4))) float f32x4;
typedef unsigned short u16;

#define B_  2
#define T_  2048
#define C_  1024
#define H_  16
#define HD_ 64

static __device__ __forceinline__ u16 f2bf(float f) {
  unsigned u = __float_as_uint(f);
  u += 0x7fffu + ((u >> 16) & 1u);   // round-to-nearest-even
  return (u16)(u >> 16);
}

// ---------------------------------------------------------------------------
// Kernel 0 "prep": three independent jobs fused into one dispatch
//   region 0 (6144 blocks): convert X,W fp32->bf16 (float4 vectorized)
//   region 1 (1024 blocks): pack V (=x per head) into MFMA-fragment layout Vf
//   region 2 ( 512 blocks): scanA partial sums SubP for the prefix scan
// ---------------------------------------------------------------------------
#define NX4 1048576   // X float4 count
#define NW4 524288    // W float4 count
__global__ __launch_bounds__(256) void prep(
    const float* __restrict__ X, const float* __restrict__ W,
    u16* __restrict__ Xb, u16* __restrict__ Wb,
    u16* __restrict__ Vf, float* __restrict__ SubP)
{
  __shared__ u16 tr[64][65];
  const int blk = blockIdx.x;
  const int tid = threadIdx.x;

  if (blk < 6144) {                       // ---- convert ----
    int i = blk * 256 + tid;
    if (i < NX4) {
      float4 v = ((const float4*)X)[i];
      ushort4 u = { f2bf(v.x), f2bf(v.y), f2bf(v.z), f2bf(v.w) };
      ((ushort4*)Xb)[i] = u;
    } else {
      int j = i - NX4;
      float4 v = ((const float4*)W)[j];
      ushort4 u = { f2bf(v.x), f2bf(v.y), f2bf(v.z), f2bf(v.w) };
      ((ushort4*)Wb)[j] = u;
    }
  } else if (blk < 6144 + 1024) {         // ---- pack_vf ----
    int idx = blk - 6144;
    const int kt = idx & 31, bh = idx >> 5;
    const int b = bh >> 4, h = bh & 15;
    {
      const int row = tid >> 2;
      const int c0  = (tid & 3) * 16;
      const float* xp = X + ((size_t)b * T_ + kt * 64 + row) * C_ + h * 64 + c0;
#pragma unroll
      for (int q = 0; q < 4; ++q) {
        float4 v = *(const float4*)(xp + q * 4);
        tr[row][c0 + q * 4 + 0] = f2bf(v.x);
        tr[row][c0 + q * 4 + 1] = f2bf(v.y);
        tr[row][c0 + q * 4 + 2] = f2bf(v.z);
        tr[row][c0 + q * 4 + 3] = f2bf(v.w);
      }
    }
    __syncthreads();
    const int w = tid >> 6, lane = tid & 63, quad = (lane >> 4), l16 = lane & 15;
    u16* outb = Vf + ((size_t)bh * 32 + kt) * 4096;
#pragma unroll
    for (int c = 0; c < 2; ++c) {   // wave w = nb
      u16 tmp[8];
#pragma unroll
      for (int j = 0; j < 8; ++j) tmp[j] = tr[c * 32 + quad * 8 + j][w * 16 + l16];
      *(bf16x8*)&outb[((w * 2 + c) * 64 + lane) * 8] = *(const bf16x8*)tmp;
    }
  } else {                                // ---- scanA ----
    int idx = blk - 7168;
    const int ch = idx & 15, bh = idx >> 4;
    const int b = bh >> 4, h = bh & 15;
    const int d = tid & 63, s = tid >> 6;
    const float* xp = X + (size_t)b * T_ * C_ + h * 64 + d;
    int t0 = ch * 128 + s * 32;
    float sum = 0.f;
#pragma unroll 8
    for (int i = 0; i < 32; ++i) sum += xp[(size_t)(t0 + i) * C_];
    SubP[((size_t)bh * 64 + ch * 4 + s) * 64 + d] = sum;
  }
}

// ---------------------------------------------------------------------------
// Kernel 1: qk = Xb @ Wb^T  (M=4096,N=2048,K=1024), 128x64 tile (1024 blocks,
// 4 blocks/CU), BK=64, global_load_lds width=16. Q row-major [B,H,T,hd];
// K written directly into MFMA-B-fragment-linear layout Kf.
// ---------------------------------------------------------------------------
__global__ __launch_bounds__(256) void gemm_qk(
    const u16* __restrict__ Xb, const u16* __restrict__ Wb,
    u16* __restrict__ Qo, u16* __restrict__ Kf)
{
  __shared__ __align__(16) u16 As[128 * 64];
  __shared__ __align__(16) u16 Bs[64 * 64];

  const int tid  = threadIdx.x;
  const int w    = tid >> 6;
  const int lane = tid & 63;
  const int quad = lane >> 4;
  const int l16  = lane & 15;
  const int m0 = blockIdx.y * 128;
  const int n0 = blockIdx.x * 64;

  f32x4 zero = {0.f, 0.f, 0.f, 0.f};
  f32x4 acc[2][4];
#pragma unroll
  for (int i = 0; i < 2; ++i)
#pragma unroll
    for (int j = 0; j < 4; ++j) acc[i][j] = zero;

  const int wr = w * 32;

  for (int k0 = 0; k0 < C_; k0 += 64) {
#pragma unroll
    for (int r = 0; r < 4; ++r) {
      const u16* ga = Xb + (size_t)(m0 + (tid >> 3) + r * 32) * C_ + k0 + (tid & 7) * 8;
      __builtin_amdgcn_global_load_lds(
          (const __attribute__((address_space(1))) void*)ga,
          (__attribute__((address_space(3))) void*)&As[tid * 8 + r * 2048],
          16, 0, 0);
    }
#pragma unroll
    for (int r = 0; r < 2; ++r) {
      const u16* gb = Wb + (size_t)(n0 + (tid >> 3) + r * 32) * C_ + k0 + (tid & 7) * 8;
      __builtin_amdgcn_global_load_lds(
          (const __attribute__((address_space(1))) void*)gb,
          (__attribute__((address_space(3))) void*)&Bs[tid * 8 + r * 2048],
          16, 0, 0);
    }
    __syncthreads();
#pragma unroll
    for (int c = 0; c < 2; ++c) {
      bf16x8 af[2], bf[4];
#pragma unroll
      for (int i = 0; i < 2; ++i)
        af[i] = *(const bf16x8*)&As[(wr + i * 16 + l16) * 64 + c * 32 + quad * 8];
#pragma unroll
      for (int j = 0; j < 4; ++j)
        bf[j] = *(const bf16x8*)&Bs[(j * 16 + l16) * 64 + c * 32 + quad * 8];
#pragma unroll
      for (int i = 0; i < 2; ++i)
#pragma unroll
        for (int j = 0; j < 4; ++j)
          acc[i][j] = __builtin_amdgcn_mfma_f32_16x16x32_bf16(af[i], bf[j], acc[i][j], 0, 0, 0);
    }
    __syncthreads();
  }

  // C/D layout: col = lane&15, row = quad*4 + reg (verified m89/m91)
  const bool isQ = (blockIdx.x < 16);
#pragma unroll
  for (int i = 0; i < 2; ++i) {
#pragma unroll
    for (int j = 0; j < 4; ++j) {
      int n = n0 + j * 16 + l16;
      if (isQ) {
        int h = n >> 6, d = n & 63;
#pragma unroll
        for (int r = 0; r < 4; ++r) {
          int m = m0 + wr + i * 16 + quad * 4 + r;
          int b = m >> 11, t = m & (T_ - 1);
          Qo[(((size_t)b * H_ + h) * T_ + t) * HD_ + d] = f2bf(acc[i][j][r]);
        }
      } else {
        int nh = n - C_;
        int hh = nh >> 6, d = nh & 63;
#pragma unroll
        for (int r = 0; r < 4; ++r) {
          int m = m0 + wr + i * 16 + quad * 4 + r;
          int b = m >> 11, t = m & (T_ - 1);
          int bh = b * H_ + hh;
          size_t idx = (((((size_t)bh * 32 + (t >> 6)) * 4 + ((t >> 4) & 3)) * 2
                         + (d >> 5)) * 64 + ((d >> 3) & 3) * 16 + (t & 15)) * 8
                       + (d & 7);
          Kf[idx] = f2bf(acc[i][j][r]);
        }
      }
    }
  }
}

// ---------------------------------------------------------------------------
// Kernel 2: scanB — finish prefix scan AND write the non-attention terms:
//   out[b,t,h*64+d] = alpha*x - gamma*SP/(t+1).  attn then does out += beta*att.
// ---------------------------------------------------------------------------
__global__ __launch_bounds__(256) void scanB(
    const float* __restrict__ X, const float* __restrict__ SubP,
    float* __restrict__ out,
    const float* __restrict__ alphap, const float* __restrict__ gammap)
{
  const int ch = blockIdx.x, bh = blockIdx.y;
  const int b = bh >> 4, h = bh & 15;
  const int d = threadIdx.x & 63, s = threadIdx.x >> 6;
  const int gs = ch * 4 + s;
  const float* pp = SubP + (size_t)bh * 64 * 64 + d;
  float base = 0.f;
  for (int i = 0; i < gs; ++i) base += pp[(size_t)i * 64];
  const float alpha = *alphap, gamma = *gammap;
  const float* xp = X + (size_t)b * T_ * C_ + h * 64 + d;
  float sum = base;
  int t0 = gs * 32;
#pragma unroll 4
  for (int i = 0; i < 32; ++i) {
    int t = t0 + i;
    float v = xp[(size_t)t * C_];
    sum += v;
    float inv = __builtin_amdgcn_rcpf((float)(t + 1));
    out[((size_t)(b * T_ + t)) * C_ + h * 64 + d] = alpha * v - gamma * sum * inv;
  }
}

// ---------------------------------------------------------------------------
// Kernel 3: software-pipelined barrier-free flash attention.
// Unroll-by-2 ping-pong K/V fragment prefetch; P through LDS as f32 with
// packed bf16 convert after the A-layout read; row sums via ones-MFMA.
// Epilogue: out += beta * acc / lsum  (alpha/gamma terms already in out).
// ---------------------------------------------------------------------------
__device__ __forceinline__ void load_kv(
    bf16x8 (&kf)[2][4], bf16x8 (&vf)[2][4],
    const u16* __restrict__ kbase, const u16* __restrict__ vbase, int lane)
{
#pragma unroll
  for (int c = 0; c < 2; ++c)
#pragma unroll
    for (int nb = 0; nb < 4; ++nb) {
      kf[c][nb] = *(const bf16x8*)&kbase[((nb * 2 + c) * 64 + lane) * 8];
      vf[c][nb] = *(const bf16x8*)&vbase[((nb * 2 + c) * 64 + lane) * 8];
    }
}

__device__ __forceinline__ void tile_compute(
    const bf16x8 (&qfrag)[2], const bf16x8 (&kf)[2][4], const bf16x8 (&vf)[2][4],
    f32x4 (&acc)[4], f32x4& accl, float (*pb)[68],
    int quad, int l16, int myrow, bool diag, bf16x8 onesf)
{
  f32x4 zero = {0.f, 0.f, 0.f, 0.f};
  f32x4 sfr[4] = {zero, zero, zero, zero};
#pragma unroll
  for (int cc = 0; cc < 2; ++cc)
#pragma unroll
    for (int nb = 0; nb < 4; ++nb)
      sfr[nb] = __builtin_amdgcn_mfma_f32_16x16x32_bf16(qfrag[cc], kf[cc][nb], sfr[nb], 0, 0, 0);

#pragma unroll
  for (int nb = 0; nb < 4; ++nb)
#pragma unroll
    for (int r = 0; r < 4; ++r) {
      float p = __expf(sfr[nb][r] * 0.125f);
      if (diag && (nb * 16 + l16 > myrow + r)) p = 0.f;
      pb[quad * 4 + r][nb * 16 + l16] = p;
    }

#pragma unroll
  for (int cc = 0; cc < 2; ++cc) {
    f32x4 plo = *(const f32x4*)&pb[l16][cc * 32 + quad * 8];
    f32x4 phi = *(const f32x4*)&pb[l16][cc * 32 + quad * 8 + 4];
    union { unsigned u[4]; bf16x8 v; } pk;
    __hip_bfloat162 hh;
    hh = __float22bfloat162_rn(make_float2(plo[0], plo[1])); pk.u[0] = *(unsigned*)&hh;
    hh = __float22bfloat162_rn(make_float2(plo[2], plo[3])); pk.u[1] = *(unsigned*)&hh;
    hh = __float22bfloat162_rn(make_float2(phi[0], phi[1])); pk.u[2] = *(unsigned*)&hh;
    hh = __float22bfloat162_rn(make_float2(phi[2], phi[3])); pk.u[3] = *(unsigned*)&hh;
    accl = __builtin_amdgcn_mfma_f32_16x16x32_bf16(pk.v, onesf, accl, 0, 0, 0);
#pragma unroll
    for (int nb = 0; nb < 4; ++nb)
      acc[nb] = __builtin_amdgcn_mfma_f32_16x16x32_bf16(pk.v, vf[cc][nb], acc[nb], 0, 0, 0);
  }
}

__global__ __launch_bounds__(256) void attn_kernel(
    const u16* __restrict__ Q, const u16* __restrict__ Kf, const u16* __restrict__ Vf,
    float* __restrict__ out, const float* __restrict__ betap)
{
  __shared__ float pbufF[4][16][68];

  const int tid  = threadIdx.x;
  const int w    = tid >> 6;
  const int lane = tid & 63;
  const int quad = lane >> 4;
  const int l16  = lane & 15;
  const int qt = 31 - blockIdx.y;        // LPT: longest blocks dispatch first
  const int bh = blockIdx.x;
  const int b = bh >> 4, h = bh & 15;

  const u16* qb  = Q  + (size_t)bh * T_ * HD_;
  const u16* kfb = Kf + (size_t)bh * T_ * HD_;
  const u16* vfb = Vf + (size_t)bh * T_ * HD_;

  bf16x8 qfrag[2];
  {
    const u16* qp = qb + (size_t)(qt * 64 + w * 16 + l16) * HD_ + quad * 8;
    qfrag[0] = *(const bf16x8*)qp;
    qfrag[1] = *(const bf16x8*)(qp + 32);
  }

  bf16x8 onesf;
#pragma unroll
  for (int j = 0; j < 8; ++j) onesf[j] = (short)0x3F80;

  f32x4 zero = {0.f, 0.f, 0.f, 0.f};
  f32x4 acc[4] = {zero, zero, zero, zero};
  f32x4 accl = zero;
  const int myrow = w * 16 + quad * 4;

  bf16x8 kA[2][4], vA[2][4], kB[2][4], vB[2][4];
  load_kv(kA, vA, kfb, vfb, lane);
  int kt = 0;
  for (;;) {
    int ktn = (kt + 1 < qt) ? kt + 1 : qt;
    load_kv(kB, vB, kfb + (size_t)ktn * 4096, vfb + (size_t)ktn * 4096, lane);
    tile_compute(qfrag, kA, vA, acc, accl, pbufF[w], quad, l16, myrow, kt == qt, onesf);
    if (kt + 1 > qt) break;
    int ktn2 = (kt + 2 < qt) ? kt + 2 : qt;
    load_kv(kA, vA, kfb + (size_t)ktn2 * 4096, vfb + (size_t)ktn2 * 4096, lane);
    tile_compute(qfrag, kB, vB, acc, accl, pbufF[w], quad, l16, myrow, kt + 1 == qt, onesf);
    kt += 2;
    if (kt > qt) break;
  }

  const float beta = *betap;
  float rl[4];
#pragma unroll
  for (int r = 0; r < 4; ++r) rl[r] = beta * __builtin_amdgcn_rcpf(accl[r]);
#pragma unroll
  for (int nb = 0; nb < 4; ++nb) {
#pragma unroll
    for (int r = 0; r < 4; ++r) {
      int t = qt * 64 + myrow + r;
      int d = nb * 16 + l16;
      size_t xi = ((size_t)b * T_ + t) * C_ + h * 64 + d;
      out[xi] = out[xi] + rl[r] * acc[nb][r];
    }
  }
}

// ---------------------------------------------------------------------------
extern "C" void kernel_launch(void* const* d_in, const int* in_sizes, int n_in,
                              void* d_out, int out_size, void* d_ws, size_t ws_size,
                              hipStream_t stream) {
  const float* x      = (const float*)d_in[0];
  const float* W_attn = (const float*)d_in[1];
  const float* alphap = (const float*)d_in[2];
  const float* betap  = (const float*)d_in[3];
  const float* gammap = (const float*)d_in[4];
  float* out = (float*)d_out;

  // ws: Qb@0(8M) Kf@8(8M) Vf@16(8M) SubP@24(1M) Xb@25(8M) Wb@33(4M) = 37M
  char* ws = (char*)d_ws;
  u16*   Qb   = (u16*)(ws);
  u16*   Kfb  = (u16*)(ws + (8ull  << 20));
  u16*   Vfb  = (u16*)(ws + (16ull << 20));
  float* SubP = (float*)(ws + (24ull << 20));
  u16*   Xb   = (u16*)(ws + (25ull << 20));
  u16*   Wb   = (u16*)(ws + (33ull << 20));

  prep<<<7680, 256, 0, stream>>>(x, W_attn, Xb, Wb, Vfb, SubP);
  gemm_qk<<<dim3(32, 32), 256, 0, stream>>>(Xb, Wb, Qb, Kfb);
  scanB<<<dim3(16, 32), 256, 0, stream>>>(x, SubP, out, alphap, gammap);
  attn_kernel<<<dim3(32, 32), 256, 0, stream>>>(Qb, Kfb, Vfb, out, betap);
}

// Round 6
// 156.051 us; speedup vs baseline: 1.1769x; 1.1769x over previous
//
#include <hip/hip_runtime.h>
#include <hip/hip_bf16.h>

typedef __attribute__((ext_vector_type(8))) short bf16x8;
typedef __attribute__((ext_vector_type(4))) float f32x4;
typedef unsigned short u16;

#define B_  2
#define T_  2048
#define C_  1024
#define H_  16
#define HD_ 64

static __device__ __forceinline__ u16 f2bf(float f) {
  unsigned u = __float_as_uint(f);
  u += 0x7fffu + ((u >> 16) & 1u);   // round-to-nearest-even
  return (u16)(u >> 16);
}

// ---------------------------------------------------------------------------
// Kernel 0 "prep": three independent jobs fused into one dispatch
//   region 0 (6144 blocks): convert X,W fp32->bf16 (float4 vectorized)
//   region 1 (1024 blocks): pack V (=x per head) into MFMA-fragment layout Vf
//   region 2 ( 512 blocks): scanA partial sums SubP (32-row chunks)
// ---------------------------------------------------------------------------
#define NX4 1048576   // X float4 count
#define NW4 524288    // W float4 count
__global__ __launch_bounds__(256) void prep(
    const float* __restrict__ X, const float* __restrict__ W,
    u16* __restrict__ Xb, u16* __restrict__ Wb,
    u16* __restrict__ Vf, float* __restrict__ SubP)
{
  __shared__ u16 tr[64][65];
  const int blk = blockIdx.x;
  const int tid = threadIdx.x;

  if (blk < 6144) {                       // ---- convert ----
    int i = blk * 256 + tid;
    if (i < NX4) {
      float4 v = ((const float4*)X)[i];
      ushort4 u = { f2bf(v.x), f2bf(v.y), f2bf(v.z), f2bf(v.w) };
      ((ushort4*)Xb)[i] = u;
    } else {
      int j = i - NX4;
      float4 v = ((const float4*)W)[j];
      ushort4 u = { f2bf(v.x), f2bf(v.y), f2bf(v.z), f2bf(v.w) };
      ((ushort4*)Wb)[j] = u;
    }
  } else if (blk < 6144 + 1024) {         // ---- pack_vf ----
    int idx = blk - 6144;
    const int kt = idx & 31, bh = idx >> 5;
    const int b = bh >> 4, h = bh & 15;
    {
      const int row = tid >> 2;
      const int c0  = (tid & 3) * 16;
      const float* xp = X + ((size_t)b * T_ + kt * 64 + row) * C_ + h * 64 + c0;
#pragma unroll
      for (int q = 0; q < 4; ++q) {
        float4 v = *(const float4*)(xp + q * 4);
        tr[row][c0 + q * 4 + 0] = f2bf(v.x);
        tr[row][c0 + q * 4 + 1] = f2bf(v.y);
        tr[row][c0 + q * 4 + 2] = f2bf(v.z);
        tr[row][c0 + q * 4 + 3] = f2bf(v.w);
      }
    }
    __syncthreads();
    const int w = tid >> 6, lane = tid & 63, quad = (lane >> 4), l16 = lane & 15;
    u16* outb = Vf + ((size_t)bh * 32 + kt) * 4096;
#pragma unroll
    for (int c = 0; c < 2; ++c) {   // wave w = nb
      u16 tmp[8];
#pragma unroll
      for (int j = 0; j < 8; ++j) tmp[j] = tr[c * 32 + quad * 8 + j][w * 16 + l16];
      *(bf16x8*)&outb[((w * 2 + c) * 64 + lane) * 8] = *(const bf16x8*)tmp;
    }
  } else {                                // ---- scanA ----
    int idx = blk - 7168;
    const int ch = idx & 15, bh = idx >> 4;
    const int b = bh >> 4, h = bh & 15;
    const int d = tid & 63, s = tid >> 6;
    const float* xp = X + (size_t)b * T_ * C_ + h * 64 + d;
    int t0 = ch * 128 + s * 32;
    float sum = 0.f;
#pragma unroll 8
    for (int i = 0; i < 32; ++i) sum += xp[(size_t)(t0 + i) * C_];
    SubP[((size_t)bh * 64 + ch * 4 + s) * 64 + d] = sum;
  }
}

// ---------------------------------------------------------------------------
// Kernel 1: qk = Xb @ Wb^T  (M=4096,N=2048,K=1024), 128x128 tile, BK=64,
// global_load_lds width=16 (m97 shape, 512 blocks = 2/CU).
// Q row-major [B,H,T,hd]; K directly into MFMA-B-fragment-linear Kf.
// ---------------------------------------------------------------------------
__global__ __launch_bounds__(256) void gemm_qk(
    const u16* __restrict__ Xb, const u16* __restrict__ Wb,
    u16* __restrict__ Qo, u16* __restrict__ Kf)
{
  __shared__ __align__(16) u16 As[128 * 64];
  __shared__ __align__(16) u16 Bs[128 * 64];

  const int tid  = threadIdx.x;
  const int w    = tid >> 6;
  const int lane = tid & 63;
  const int quad = lane >> 4;
  const int l16  = lane & 15;
  const int m0 = blockIdx.y * 128;
  const int n0 = blockIdx.x * 128;

  const int grow = w * 8 + ((lane >> 3) & 7);
  const int gcol = (lane & 7) * 8;

  f32x4 zero = {0.f, 0.f, 0.f, 0.f};
  f32x4 acc[4][4];
#pragma unroll
  for (int i = 0; i < 4; ++i)
#pragma unroll
    for (int j = 0; j < 4; ++j) acc[i][j] = zero;

  const int wr = (w >> 1) * 64, wc = (w & 1) * 64;

  for (int k0 = 0; k0 < C_; k0 += 64) {
#pragma unroll
    for (int r = 0; r < 4; ++r) {
      const u16* ga = Xb + (size_t)(m0 + grow + r * 32) * C_ + k0 + gcol;
      const u16* gb = Wb + (size_t)(n0 + grow + r * 32) * C_ + k0 + gcol;
      __builtin_amdgcn_global_load_lds(
          (const __attribute__((address_space(1))) void*)ga,
          (__attribute__((address_space(3))) void*)&As[(w * 8 + r * 32) * 64],
          16, 0, 0);
      __builtin_amdgcn_global_load_lds(
          (const __attribute__((address_space(1))) void*)gb,
          (__attribute__((address_space(3))) void*)&Bs[(w * 8 + r * 32) * 64],
          16, 0, 0);
    }
    __syncthreads();
#pragma unroll
    for (int c = 0; c < 2; ++c) {
      bf16x8 af[4], bf[4];
#pragma unroll
      for (int i = 0; i < 4; ++i)
        af[i] = *(const bf16x8*)&As[(wr + i * 16 + l16) * 64 + c * 32 + quad * 8];
#pragma unroll
      for (int j = 0; j < 4; ++j)
        bf[j] = *(const bf16x8*)&Bs[(wc + j * 16 + l16) * 64 + c * 32 + quad * 8];
#pragma unroll
      for (int i = 0; i < 4; ++i)
#pragma unroll
        for (int j = 0; j < 4; ++j)
          acc[i][j] = __builtin_amdgcn_mfma_f32_16x16x32_bf16(af[i], bf[j], acc[i][j], 0, 0, 0);
    }
    __syncthreads();
  }

  // C/D layout: col = lane&15, row = quad*4 + reg (verified m89/m91)
#pragma unroll
  for (int i = 0; i < 4; ++i) {
#pragma unroll
    for (int j = 0; j < 4; ++j) {
      int n = n0 + wc + j * 16 + l16;   // wave-uniform branch (64-aligned base)
      if (n < C_) {
        int h = n >> 6, d = n & 63;
#pragma unroll
        for (int r = 0; r < 4; ++r) {
          int m = m0 + wr + i * 16 + quad * 4 + r;
          int b = m >> 11, t = m & (T_ - 1);
          Qo[(((size_t)b * H_ + h) * T_ + t) * HD_ + d] = f2bf(acc[i][j][r]);
        }
      } else {
        int nh = n - C_;
        int hh = nh >> 6, d = nh & 63;
#pragma unroll
        for (int r = 0; r < 4; ++r) {
          int m = m0 + wr + i * 16 + quad * 4 + r;
          int b = m >> 11, t = m & (T_ - 1);
          int bh = b * H_ + hh;
          size_t idx = (((((size_t)bh * 32 + (t >> 6)) * 4 + ((t >> 4) & 3)) * 2
                         + (d >> 5)) * 64 + ((d >> 3) & 3) * 16 + (t & 15)) * 8
                       + (d & 7);
          Kf[idx] = f2bf(acc[i][j][r]);
        }
      }
    }
  }
}

// ---------------------------------------------------------------------------
// Kernel 2: software-pipelined barrier-free flash attention + FULL fused
// epilogue (prefix-scan finish + alpha/gamma terms -> write-only out).
// ---------------------------------------------------------------------------
__device__ __forceinline__ void load_kv(
    bf16x8 (&kf)[2][4], bf16x8 (&vf)[2][4],
    const u16* __restrict__ kbase, const u16* __restrict__ vbase, int lane)
{
#pragma unroll
  for (int c = 0; c < 2; ++c)
#pragma unroll
    for (int nb = 0; nb < 4; ++nb) {
      kf[c][nb] = *(const bf16x8*)&kbase[((nb * 2 + c) * 64 + lane) * 8];
      vf[c][nb] = *(const bf16x8*)&vbase[((nb * 2 + c) * 64 + lane) * 8];
    }
}

__device__ __forceinline__ void tile_compute(
    const bf16x8 (&qfrag)[2], const bf16x8 (&kf)[2][4], const bf16x8 (&vf)[2][4],
    f32x4 (&acc)[4], f32x4& accl, float (*pb)[68],
    int quad, int l16, int myrow, bool diag, bf16x8 onesf)
{
  f32x4 zero = {0.f, 0.f, 0.f, 0.f};
  f32x4 sfr[4] = {zero, zero, zero, zero};
#pragma unroll
  for (int cc = 0; cc < 2; ++cc)
#pragma unroll
    for (int nb = 0; nb < 4; ++nb)
      sfr[nb] = __builtin_amdgcn_mfma_f32_16x16x32_bf16(qfrag[cc], kf[cc][nb], sfr[nb], 0, 0, 0);

#pragma unroll
  for (int nb = 0; nb < 4; ++nb)
#pragma unroll
    for (int r = 0; r < 4; ++r) {
      float p = __expf(sfr[nb][r] * 0.125f);
      if (diag && (nb * 16 + l16 > myrow + r)) p = 0.f;
      pb[quad * 4 + r][nb * 16 + l16] = p;
    }

#pragma unroll
  for (int cc = 0; cc < 2; ++cc) {
    f32x4 plo = *(const f32x4*)&pb[l16][cc * 32 + quad * 8];
    f32x4 phi = *(const f32x4*)&pb[l16][cc * 32 + quad * 8 + 4];
    union { unsigned u[4]; bf16x8 v; } pk;
    __hip_bfloat162 hh;
    hh = __float22bfloat162_rn(make_float2(plo[0], plo[1])); pk.u[0] = *(unsigned*)&hh;
    hh = __float22bfloat162_rn(make_float2(plo[2], plo[3])); pk.u[1] = *(unsigned*)&hh;
    hh = __float22bfloat162_rn(make_float2(phi[0], phi[1])); pk.u[2] = *(unsigned*)&hh;
    hh = __float22bfloat162_rn(make_float2(phi[2], phi[3])); pk.u[3] = *(unsigned*)&hh;
    accl = __builtin_amdgcn_mfma_f32_16x16x32_bf16(pk.v, onesf, accl, 0, 0, 0);
#pragma unroll
    for (int nb = 0; nb < 4; ++nb)
      acc[nb] = __builtin_amdgcn_mfma_f32_16x16x32_bf16(pk.v, vf[cc][nb], acc[nb], 0, 0, 0);
  }
}

__global__ __launch_bounds__(256) void attn_kernel(
    const u16* __restrict__ Q, const u16* __restrict__ Kf, const u16* __restrict__ Vf,
    const float* __restrict__ SubP, const float* __restrict__ X, float* __restrict__ out,
    const float* __restrict__ alphap, const float* __restrict__ betap,
    const float* __restrict__ gammap)
{
  // smem: main phase = pbufF[4][16][68] f32 (17408 B);
  // epilogue aliases: Xt[64][68] f32 (17408 B) + G[4][64] + GP[4][64] (2048 B)
  __shared__ __align__(16) char smem[19456];

  const int tid  = threadIdx.x;
  const int w    = tid >> 6;
  const int lane = tid & 63;
  const int quad = lane >> 4;
  const int l16  = lane & 15;
  const int qt = 31 - blockIdx.y;        // LPT: longest blocks dispatch first
  const int bh = blockIdx.x;
  const int b = bh >> 4, h = bh & 15;

  const u16* qb  = Q  + (size_t)bh * T_ * HD_;
  const u16* kfb = Kf + (size_t)bh * T_ * HD_;
  const u16* vfb = Vf + (size_t)bh * T_ * HD_;

  bf16x8 qfrag[2];
  {
    const u16* qp = qb + (size_t)(qt * 64 + w * 16 + l16) * HD_ + quad * 8;
    qfrag[0] = *(const bf16x8*)qp;
    qfrag[1] = *(const bf16x8*)(qp + 32);
  }

  bf16x8 onesf;
#pragma unroll
  for (int j = 0; j < 8; ++j) onesf[j] = (short)0x3F80;

  f32x4 zero = {0.f, 0.f, 0.f, 0.f};
  f32x4 acc[4] = {zero, zero, zero, zero};
  f32x4 accl = zero;
  const int myrow = w * 16 + quad * 4;
  float (*pb)[68] = (float(*)[68])((float*)smem + (size_t)w * 16 * 68);

  bf16x8 kA[2][4], vA[2][4], kB[2][4], vB[2][4];
  load_kv(kA, vA, kfb, vfb, lane);
  int kt = 0;
  for (;;) {
    int ktn = (kt + 1 < qt) ? kt + 1 : qt;
    load_kv(kB, vB, kfb + (size_t)ktn * 4096, vfb + (size_t)ktn * 4096, lane);
    tile_compute(qfrag, kA, vA, acc, accl, pb, quad, l16, myrow, kt == qt, onesf);
    if (kt + 1 > qt) break;
    int ktn2 = (kt + 2 < qt) ? kt + 2 : qt;
    load_kv(kA, vA, kfb + (size_t)ktn2 * 4096, vfb + (size_t)ktn2 * 4096, lane);
    tile_compute(qfrag, kB, vB, acc, accl, pb, quad, l16, myrow, kt + 1 == qt, onesf);
    kt += 2;
    if (kt > qt) break;
  }

  // ---------------- fused epilogue ----------------
  __syncthreads();                        // all waves done with pbufF
  float* Xt = (float*)smem;               // [64][68]
  float* G  = (float*)(smem + 17408);     // [4][64]
  float* GP = (float*)(smem + 18432);     // [4][64]

  // stage this block's X tile (fp32): rows t = qt*64 .. +64, cols h*64 .. +64
  {
    const int row = tid >> 2, c0 = (tid & 3) * 16;
    const float* xp = X + ((size_t)b * T_ + qt * 64 + row) * C_ + h * 64 + c0;
#pragma unroll
    for (int q = 0; q < 4; ++q) {
      float4 v = *(const float4*)(xp + q * 4);
      Xt[row * 68 + c0 + q * 4 + 0] = v.x;
      Xt[row * 68 + c0 + q * 4 + 1] = v.y;
      Xt[row * 68 + c0 + q * 4 + 2] = v.z;
      Xt[row * 68 + c0 + q * 4 + 3] = v.w;
    }
  }
  // prefix base from SubP (32-row partials), strided across waves
  {
    float p = 0.f;
    for (int i = w; i < 2 * qt; i += 4)
      p += SubP[(size_t)bh * 4096 + i * 64 + lane];
    GP[w * 64 + lane] = p;
  }
  __syncthreads();
  // per-wave 16-row partial sums of the X tile
  {
    float g = 0.f;
#pragma unroll
    for (int i = 0; i < 16; ++i) g += Xt[(w * 16 + i) * 68 + lane];
    G[w * 64 + lane] = g;
  }
  __syncthreads();
  // in-place scan: Xt[i][d] := alpha*x - gamma*SP(t)/(t+1)
  {
    const float alpha = *alphap, gamma = *gammap;
    float run = GP[lane] + GP[64 + lane] + GP[128 + lane] + GP[192 + lane];
    for (int g = 0; g < w; ++g) run += G[g * 64 + lane];
    const int tbase = qt * 64 + w * 16;
#pragma unroll
    for (int i = 0; i < 16; ++i) {
      float v = Xt[(w * 16 + i) * 68 + lane];
      run += v;
      Xt[(w * 16 + i) * 68 + lane] =
          alpha * v - gamma * run * __builtin_amdgcn_rcpf((float)(tbase + i + 1));
    }
  }
  __syncthreads();

  const float beta = *betap;
  float rl[4];
#pragma unroll
  for (int r = 0; r < 4; ++r) rl[r] = beta * __builtin_amdgcn_rcpf(accl[r]);
#pragma unroll
  for (int nb = 0; nb < 4; ++nb) {
#pragma unroll
    for (int r = 0; r < 4; ++r) {
      int t = qt * 64 + myrow + r;
      int d = nb * 16 + l16;
      out[((size_t)b * T_ + t) * C_ + h * 64 + d] =
          Xt[(myrow + r) * 68 + d] + rl[r] * acc[nb][r];
    }
  }
}

// ---------------------------------------------------------------------------
extern "C" void kernel_launch(void* const* d_in, const int* in_sizes, int n_in,
                              void* d_out, int out_size, void* d_ws, size_t ws_size,
                              hipStream_t stream) {
  const float* x      = (const float*)d_in[0];
  const float* W_attn = (const float*)d_in[1];
  const float* alphap = (const float*)d_in[2];
  const float* betap  = (const float*)d_in[3];
  const float* gammap = (const float*)d_in[4];
  float* out = (float*)d_out;

  // ws: Qb@0(8M) Kf@8(8M) Vf@16(8M) SubP@24(1M) Xb@25(8M) Wb@33(4M) = 37M
  char* ws = (char*)d_ws;
  u16*   Qb   = (u16*)(ws);
  u16*   Kfb  = (u16*)(ws + (8ull  << 20));
  u16*   Vfb  = (u16*)(ws + (16ull << 20));
  float* SubP = (float*)(ws + (24ull << 20));
  u16*   Xb   = (u16*)(ws + (25ull << 20));
  u16*   Wb   = (u16*)(ws + (33ull << 20));

  prep<<<7680, 256, 0, stream>>>(x, W_attn, Xb, Wb, Vfb, SubP);
  gemm_qk<<<dim3(16, 32), 256, 0, stream>>>(Xb, Wb, Qb, Kfb);
  attn_kernel<<<dim3(32, 32), 256, 0, stream>>>(Qb, Kfb, Vfb, SubP, x, out,
                                                alphap, betap, gammap);
}